// Round 12
// baseline (444.080 us; speedup 1.0000x reference)
//
#include <hip/hip_runtime.h>
#include <hip/hip_bf16.h>
#include <math.h>
#include <stdint.h>

typedef __bf16 bf16_t;
typedef bf16_t bf16x2 __attribute__((ext_vector_type(2)));
typedef bf16_t bf16x4 __attribute__((ext_vector_type(4)));
typedef bf16_t bf16x8 __attribute__((ext_vector_type(8)));
typedef float floatx4 __attribute__((ext_vector_type(4)));

#define B_     4
#define S_     4096
#define D_     1024
#define P_     1364
#define P3_    4092      // 3*P
#define NP_    5456      // 3P + P
#define NPAD_  5504      // act row stride
#define NB_    5632      // GEMM1 N padded to 22 tiles of 256
#define KPAD_  1408      // P_ padded (K of out-GEMM, 22 K-tiles)
#define ROWS_  16384     // B*S
#define CAP_   15.0f
#define EPS_   1e-6f
#define CHUNKS_ 32
#define CLEN_   128      // S_/CHUNKS_

// ---------------- fast transcendentals (bf16-accuracy) ----------------
__device__ __forceinline__ float fast_tanh(float x) {
    x = fminf(fmaxf(x, -15.f), 15.f);
    float e = __expf(2.f * x);
    return __fdividef(e - 1.f, e + 1.f);
}
// sigmoid(CAP*tanh(g/CAP)) == sigmoid(g) to <0.002 for all g.
__device__ __forceinline__ float fast_sig(float g) {
    return __fdividef(1.f, 1.f + __expf(-g));
}

__device__ __forceinline__ void vmcnt0() {
    asm volatile("s_waitcnt vmcnt(0)" ::: "memory");
}
__device__ __forceinline__ void vmcnt8() {
    asm volatile("s_waitcnt vmcnt(8)" ::: "memory");
}

// ---------------- RMSNorm: x fp32 [ROWS][D] -> xn bf16 [ROWS][D] ----------------
__global__ __launch_bounds__(256) void rmsnorm_kernel(const float* __restrict__ x,
                                                      const float* __restrict__ w,
                                                      bf16_t* __restrict__ xn) {
    int row = blockIdx.x;
    int tid = threadIdx.x;
    const float4 v = ((const float4*)(x + (size_t)row * D_))[tid];
    float ss = v.x * v.x + v.y * v.y + v.z * v.z + v.w * v.w;
    #pragma unroll
    for (int off = 32; off > 0; off >>= 1) ss += __shfl_down(ss, off);
    __shared__ float red[4];
    if ((tid & 63) == 0) red[tid >> 6] = ss;
    __syncthreads();
    float tot = red[0] + red[1] + red[2] + red[3];
    float scale = rsqrtf(tot * (1.0f / (float)D_) + EPS_);
    const float4 wv = ((const float4*)w)[tid];
    bf16x4 o;
    o[0] = (bf16_t)(v.x * scale * wv.x);
    o[1] = (bf16_t)(v.y * scale * wv.y);
    o[2] = (bf16_t)(v.z * scale * wv.z);
    o[3] = (bf16_t)(v.w * scale * wv.w);
    ((bf16x4*)(xn + (size_t)row * D_))[tid] = o;
}

// ---- pack W_gate [D][3P] + W_cell [D][P] fp32 -> Wcat^T bf16 [NB_][D] ----
__global__ __launch_bounds__(256) void pack_wcat(const float* __restrict__ Wg,
                                                 const float* __restrict__ Wc,
                                                 bf16_t* __restrict__ Wt) {
    __shared__ float tile[32][33];
    int kt = blockIdx.x * 32;
    int nt = blockIdx.y * 32;
    int tx = threadIdx.x & 31;
    int ty = threadIdx.x >> 5;
    #pragma unroll
    for (int i = 0; i < 4; i++) {
        int k = kt + ty + 8 * i;
        int n = nt + tx;
        float val = 0.f;
        if (n < P3_)      val = Wg[(size_t)k * P3_ + n];
        else if (n < NP_) val = Wc[(size_t)k * P_ + (n - P3_)];
        tile[ty + 8 * i][tx] = val;
    }
    __syncthreads();
    #pragma unroll
    for (int i = 0; i < 4; i++) {
        int n = nt + ty + 8 * i;
        int k = kt + tx;
        Wt[(size_t)n * D_ + k] = (bf16_t)tile[tx][ty + 8 * i];
    }
}

// ---- pack W_out [P][D] fp32 -> Wout^T bf16 [D][KPAD_] ----
__global__ __launch_bounds__(256) void pack_wout(const float* __restrict__ Wo,
                                                 bf16_t* __restrict__ Wt) {
    __shared__ float tile[32][33];
    int pt = blockIdx.x * 32;
    int dt = blockIdx.y * 32;
    int tx = threadIdx.x & 31;
    int ty = threadIdx.x >> 5;
    #pragma unroll
    for (int i = 0; i < 4; i++) {
        int p = pt + ty + 8 * i;
        int d = dt + tx;
        float val = (p < P_) ? Wo[(size_t)p * D_ + d] : 0.f;
        tile[ty + 8 * i][tx] = val;
    }
    __syncthreads();
    #pragma unroll
    for (int i = 0; i < 4; i++) {
        int d = dt + ty + 8 * i;
        int p = pt + tx;
        Wt[(size_t)d * KPAD_ + p] = (bf16_t)tile[tx][ty + 8 * i];
    }
}

// ---------------- 256x256 8-wave GEMM, 1 barrier/phase + spread staging ----------------
// Per phase: {ds_reads; stage?; setprio; MFMA; setprio; barrier}. The pre-MFMA
// barrier is REMOVED: each wave's reads are lgkm-retired before its own phase-end
// MFMA (compiler def-use waits), so the phase-end barrier alone certifies stage
// WAR; dropping lockstep lets wave X's MFMAs overlap wave Y's reads (m114).
// Quadrant order Q1(m0-3,n0-1) Q2(m0-3,n2-3) Q3(m4-7,n2-3) Q4(m4-7,n0-1);
// stage t+2 INTO BUF c as regions free: B-lo@ph2, A-lo@ph3, A-hi+B-hi@ph4.
// End-of-tile counted vmcnt(8) retires exactly t+1's 8 units (FIFO); never
// drains mid-loop (T4). Zero-conflict swizzle (r3+). Operand-swap mfma(B,A).
template <int KTOT, int LDA, int LDB, int LDC, int NX, int EPI>
__global__ __launch_bounds__(512, 2) void gemm8(const bf16_t* __restrict__ A,
                                                const bf16_t* __restrict__ Bt,
                                                const float* __restrict__ res,
                                                void* __restrict__ outv) {
    constexpr int NT = KTOT / 64;
    static_assert(NT >= 4, "NT >= 4");
    __shared__ __align__(16) char smem[131072];

    const int tid  = threadIdx.x;
    const int wid  = tid >> 6;
    const int lane = tid & 63;
    const int l15  = lane & 15;
    const int sl4  = lane >> 4;
    const int sp    = sl4 ^ ((lane >> 1) & 3);          // read 16B-slot swizzle
    const int chunk = (lane & 3) ^ ((lane >> 3) & 3);   // stage-source inverse swizzle
    const int wrow = (wid >> 2) * 128;
    const int wcol = (wid & 3) * 64;

    // XCD map (verified: FETCH ~= compulsory): xcd owns 8 by-rows, bx-outer
    constexpr int MCH = (ROWS_ / 256) / 8;   // 8
    const int bid = blockIdx.x;
    const int xcd = bid & 7;
    const int idx = bid >> 3;
    const int bx  = idx / MCH;
    const int by  = xcd * MCH + (idx - bx * MCH);
    const int m0 = by * 256, n0 = bx * 256;

    const int srow = wid * 16 + (lane >> 2);
    const bf16_t* Asrc = A  + (size_t)(m0 + srow) * LDA + chunk * 8;
    const bf16_t* Bsrc = Bt + (size_t)(n0 + srow) * LDB + chunk * 8;
    const unsigned ldsA0 = (unsigned)(wid * 1024);
    const unsigned ldsB0 = 32768u + (unsigned)(wid * 1024);

    // half-unit stages: 2 global_load_lds each (one per kk)
    auto stageAlo = [&](int kt, int buf) {   // A rows 0-127
        #pragma unroll
        for (int kk = 0; kk < 2; kk++)
            __builtin_amdgcn_global_load_lds(
                (const unsigned*)(Asrc + kt * 64 + kk * 32),
                (unsigned*)(smem + ((unsigned)buf * 65536u + (unsigned)kk * 16384u + ldsA0)), 16, 0, 0);
    };
    auto stageAhi = [&](int kt, int buf) {   // A rows 128-255
        #pragma unroll
        for (int kk = 0; kk < 2; kk++)
            __builtin_amdgcn_global_load_lds(
                (const unsigned*)(Asrc + (size_t)128 * LDA + kt * 64 + kk * 32),
                (unsigned*)(smem + ((unsigned)buf * 65536u + (unsigned)kk * 16384u + 8192u + ldsA0)), 16, 0, 0);
    };
    auto stageBlo = [&](int kt, int buf) {   // B rows (out-cols) 0-127
        #pragma unroll
        for (int kk = 0; kk < 2; kk++)
            __builtin_amdgcn_global_load_lds(
                (const unsigned*)(Bsrc + kt * 64 + kk * 32),
                (unsigned*)(smem + ((unsigned)buf * 65536u + (unsigned)kk * 16384u + ldsB0)), 16, 0, 0);
    };
    auto stageBhi = [&](int kt, int buf) {   // B rows 128-255
        #pragma unroll
        for (int kk = 0; kk < 2; kk++)
            __builtin_amdgcn_global_load_lds(
                (const unsigned*)(Bsrc + (size_t)128 * LDB + kt * 64 + kk * 32),
                (unsigned*)(smem + ((unsigned)buf * 65536u + (unsigned)kk * 16384u + 8192u + ldsB0)), 16, 0, 0);
    };
    auto ldA = [&](int buf, int kk, int m) -> bf16x8 {
        return *(const bf16x8*)(smem + (buf * 65536 + kk * 16384 +
                                        (wrow + m * 16 + l15) * 64 + sp * 16));
    };
    auto ldB = [&](int buf, int kk, int n) -> bf16x8 {
        return *(const bf16x8*)(smem + (buf * 65536 + 32768 + kk * 16384 +
                                        (wcol + n * 16 + l15) * 64 + sp * 16));
    };

    floatx4 acc[8][4];
    #pragma unroll
    for (int m = 0; m < 8; m++)
        #pragma unroll
        for (int n = 0; n < 4; n++) acc[m][n] = (floatx4){0.f, 0.f, 0.f, 0.f};

    bf16x8 aq[8];   // A: [0..3]=kk0 m-set, [4..7]=kk1 m-set (lo then hi, rotated ph3)
    bf16x8 bq[4];   // B n0-1: live ph1 -> ph4
    bf16x8 bq2[4];  // B n2-3

    // prologue: tiles 0,1 fully staged (16 loads); counted wait retires tile0
    stageAlo(0, 0); stageAhi(0, 0); stageBlo(0, 0); stageBhi(0, 0);
    stageAlo(1, 1); stageAhi(1, 1); stageBlo(1, 1); stageBhi(1, 1);
    vmcnt8();
    __builtin_amdgcn_s_barrier();

    for (int t = 0; t < NT; ++t) {
        const int c = t & 1;
        const bool st = (t + 2 < NT);

        // ---- ph1: 12 reads (A-lo both kk, B-lo both kk); MFMA Q1
        #pragma unroll
        for (int m = 0; m < 4; m++) { aq[m] = ldA(c, 0, m); aq[m + 4] = ldA(c, 1, m); }
        #pragma unroll
        for (int n = 0; n < 2; n++) { bq[n] = ldB(c, 0, n); bq[n + 2] = ldB(c, 1, n); }
        __builtin_amdgcn_s_setprio(1);
        #pragma unroll
        for (int m = 0; m < 4; m++)
            #pragma unroll
            for (int n = 0; n < 2; n++) {
                acc[m][n] = __builtin_amdgcn_mfma_f32_16x16x32_bf16(bq[n], aq[m], acc[m][n], 0, 0, 0);
                acc[m][n] = __builtin_amdgcn_mfma_f32_16x16x32_bf16(bq[n + 2], aq[m + 4], acc[m][n], 0, 0, 0);
            }
        __builtin_amdgcn_s_setprio(0);
        __builtin_amdgcn_s_barrier();   // all waves' A-lo/B-lo reads retired

        // ---- ph2: 4 reads (B-hi); stage B-lo(t+2) into freed region; MFMA Q2
        #pragma unroll
        for (int n = 0; n < 2; n++) { bq2[n] = ldB(c, 0, n + 2); bq2[n + 2] = ldB(c, 1, n + 2); }
        if (st) stageBlo(t + 2, c);
        __builtin_amdgcn_s_setprio(1);
        #pragma unroll
        for (int m = 0; m < 4; m++)
            #pragma unroll
            for (int n = 0; n < 2; n++) {
                acc[m][n + 2] = __builtin_amdgcn_mfma_f32_16x16x32_bf16(bq2[n], aq[m], acc[m][n + 2], 0, 0, 0);
                acc[m][n + 2] = __builtin_amdgcn_mfma_f32_16x16x32_bf16(bq2[n + 2], aq[m + 4], acc[m][n + 2], 0, 0, 0);
            }
        __builtin_amdgcn_s_setprio(0);
        __builtin_amdgcn_s_barrier();

        // ---- ph3: 8 reads (A-hi overwrite aq); stage A-lo(t+2); MFMA Q3
        #pragma unroll
        for (int m = 0; m < 4; m++) { aq[m] = ldA(c, 0, m + 4); aq[m + 4] = ldA(c, 1, m + 4); }
        if (st) stageAlo(t + 2, c);
        __builtin_amdgcn_s_setprio(1);
        #pragma unroll
        for (int m = 0; m < 4; m++)
            #pragma unroll
            for (int n = 0; n < 2; n++) {
                acc[m + 4][n + 2] = __builtin_amdgcn_mfma_f32_16x16x32_bf16(bq2[n], aq[m], acc[m + 4][n + 2], 0, 0, 0);
                acc[m + 4][n + 2] = __builtin_amdgcn_mfma_f32_16x16x32_bf16(bq2[n + 2], aq[m + 4], acc[m + 4][n + 2], 0, 0, 0);
            }
        __builtin_amdgcn_s_setprio(0);
        __builtin_amdgcn_s_barrier();   // all waves' A-hi/B-hi reads retired

        // ---- ph4: stage A-hi+B-hi(t+2); reg-only Q4; counted vmcnt; publish
        if (st) { stageAhi(t + 2, c); stageBhi(t + 2, c); }
        __builtin_amdgcn_s_setprio(1);
        #pragma unroll
        for (int m = 0; m < 4; m++)
            #pragma unroll
            for (int n = 0; n < 2; n++) {
                acc[m + 4][n] = __builtin_amdgcn_mfma_f32_16x16x32_bf16(bq[n], aq[m], acc[m + 4][n], 0, 0, 0);
                acc[m + 4][n] = __builtin_amdgcn_mfma_f32_16x16x32_bf16(bq[n + 2], aq[m + 4], acc[m + 4][n], 0, 0, 0);
            }
        __builtin_amdgcn_s_setprio(0);
        if (st)                vmcnt8();   // retire t+1's 8 units; t+2's stay in flight
        else if (t + 2 == NT)  vmcnt0();   // tail: only t+1's units outstanding
        __builtin_amdgcn_s_barrier();      // publish buf c^1
    }

    // transposed C/D (operand swap): lane holds rows m0+wrow+m*16+l15,
    // 4 consecutive cols n0+wcol+n*16+sl4*4 .. +3
    if constexpr (EPI == 0) {
        bf16_t* O = (bf16_t*)outv;
        #pragma unroll
        for (int m = 0; m < 8; m++) {
            const int row = m0 + wrow + m * 16 + l15;
            #pragma unroll
            for (int n = 0; n < 4; n++) {
                const int cb = n0 + wcol + n * 16 + sl4 * 4;
                if (cb < NP_) {           // packs never straddle NP_/P3_ (all %4==0)
                    const bool sg = cb < P3_;
                    bf16x4 o;
                    #pragma unroll
                    for (int r = 0; r < 4; r++) {
                        float g = acc[m][n][r];
                        o[r] = (bf16_t)(sg ? fast_sig(g) : fast_tanh(g));
                    }
                    *(bf16x4*)(O + (size_t)row * LDC + cb) = o;
                }
            }
        }
    } else {
        float* O = (float*)outv;
        #pragma unroll
        for (int m = 0; m < 8; m++) {
            const int row = m0 + wrow + m * 16 + l15;
            #pragma unroll
            for (int n = 0; n < 4; n++) {
                const int cb = n0 + wcol + n * 16 + sl4 * 4;
                const float4 rv = *(const float4*)(res + (size_t)row * LDC + cb);
                float4 ov;
                ov.x = rv.x + acc[m][n][0];
                ov.y = rv.y + acc[m][n][1];
                ov.z = rv.z + acc[m][n][2];
                ov.w = rv.w + acc[m][n][3];
                *(float4*)(O + (size_t)row * LDC + cb) = ov;
            }
        }
    }
}

// ---------------- chunked linear recurrence (x2 vectorized, CHUNKS=32) ----------------
// act layout per row (bf16, stride NPAD_): [0,P): i | [P,2P): f | [2P,3P): o | [3P,4P): tanh(c)
__global__ __launch_bounds__(256) void chunk_scan1(const bf16_t* __restrict__ act,
                                                   float* __restrict__ FA) {
    int p = (blockIdx.x * 256 + threadIdx.x) * 2;
    int c = blockIdx.y;
    int b = blockIdx.z;
    if (p >= P_) return;       // P_ even: pairs never straddle
    const bf16_t* base = act + (size_t)(b * S_ + c * CLEN_) * NPAD_;
    float F0 = 1.f, F1 = 1.f, A0 = 0.f, A1 = 0.f;
    for (int t = 0; t < CLEN_; t++) {
        const bf16_t* r = base + (size_t)t * NPAD_;
        bf16x2 iv = *(const bf16x2*)(r + p);
        bf16x2 fv = *(const bf16x2*)(r + P_ + p);
        bf16x2 tc = *(const bf16x2*)(r + P3_ + p);
        float f0 = (float)fv[0], f1 = (float)fv[1];
        A0 = f0 * A0 + (float)iv[0] * (float)tc[0];
        A1 = f1 * A1 + (float)iv[1] * (float)tc[1];
        F0 *= f0; F1 *= f1;
    }
    float4 o; o.x = F0; o.y = A0; o.z = F1; o.w = A1;
    *(float4*)(FA + (((size_t)b * CHUNKS_ + c) * P_ + p) * 2) = o;  // 16B aligned (p even)
}

__global__ __launch_bounds__(256) void chunk_scan2(const bf16_t* __restrict__ act,
                                                   const float* __restrict__ FA,
                                                   const float* __restrict__ h0,
                                                   bf16_t* __restrict__ outp) {
    int p = (blockIdx.x * 256 + threadIdx.x) * 2;
    int c = blockIdx.y;
    int b = blockIdx.z;
    if (p >= KPAD_) return;
    bf16_t* ob = outp + (size_t)(b * S_ + c * CLEN_) * KPAD_;
    if (p >= P_) {  // zero-fill K-pad columns for GEMM2
        bf16x2 z; z[0] = (bf16_t)0.f; z[1] = (bf16_t)0.f;
        for (int t = 0; t < CLEN_; t++)
            *(bf16x2*)(ob + (size_t)t * KPAD_ + p) = z;
        return;
    }
    float h0v = h0[(size_t)b * P_ + p];
    float h1v = h0[(size_t)b * P_ + p + 1];
    for (int j = 0; j < c; j++) {
        float4 fa = *(const float4*)(FA + (((size_t)b * CHUNKS_ + j) * P_ + p) * 2);
        h0v = fa.y + fa.x * h0v;
        h1v = fa.w + fa.z * h1v;
    }
    const bf16_t* base = act + (size_t)(b * S_ + c * CLEN_) * NPAD_;
    for (int t = 0; t < CLEN_; t++) {
        const bf16_t* r = base + (size_t)t * NPAD_;
        bf16x2 iv = *(const bf16x2*)(r + p);
        bf16x2 fv = *(const bf16x2*)(r + P_ + p);
        bf16x2 ov = *(const bf16x2*)(r + 2 * P_ + p);
        bf16x2 tc = *(const bf16x2*)(r + P3_ + p);
        h0v = (float)fv[0] * h0v + (float)iv[0] * (float)tc[0];
        h1v = (float)fv[1] * h1v + (float)iv[1] * (float)tc[1];
        bf16x2 o;
        o[0] = (bf16_t)((float)ov[0] * fast_tanh(h0v));
        o[1] = (bf16_t)((float)ov[1] * fast_tanh(h1v));
        *(bf16x2*)(ob + (size_t)t * KPAD_ + p) = o;
    }
}

__global__ void copy_hidden(const float* __restrict__ hs, float* __restrict__ dst) {
    int i = blockIdx.x * 256 + threadIdx.x;
    if (i < B_ * P_) dst[i] = hs[i];
}

extern "C" void kernel_launch(void* const* d_in, const int* in_sizes, int n_in,
                              void* d_out, int out_size, void* d_ws, size_t ws_size,
                              hipStream_t stream) {
    const float* x   = (const float*)d_in[0];
    const float* hs  = (const float*)d_in[1];
    const float* lnw = (const float*)d_in[2];
    const float* Wg  = (const float*)d_in[3];
    const float* Wc  = (const float*)d_in[4];
    const float* Wo  = (const float*)d_in[5];
    float* out = (float*)d_out;

    char* ws = (char*)d_ws;
    size_t off = 0;
    auto alloc = [&](size_t bytes) {
        void* p = ws + off;
        off += (bytes + 255) & ~(size_t)255;
        return p;
    };
    bf16_t* xn_outp = (bf16_t*)alloc((size_t)ROWS_ * KPAD_ * 2);   // xn then outputs
    bf16_t* act     = (bf16_t*)alloc((size_t)ROWS_ * NPAD_ * 2);
    bf16_t* WcatT   = (bf16_t*)alloc((size_t)NB_ * D_ * 2);
    bf16_t* WoutT   = (bf16_t*)alloc((size_t)D_ * KPAD_ * 2);
    float*  FA      = (float*)alloc((size_t)B_ * CHUNKS_ * P_ * 2 * 4);

    bf16_t* xn   = xn_outp;
    bf16_t* outp = xn_outp;

    hipLaunchKernelGGL(rmsnorm_kernel, dim3(ROWS_), dim3(256), 0, stream, x, lnw, xn);
    hipLaunchKernelGGL(pack_wcat, dim3(32, NB_ / 32), dim3(256), 0, stream, Wg, Wc, WcatT);
    hipLaunchKernelGGL(pack_wout, dim3(KPAD_ / 32, D_ / 32), dim3(256), 0, stream, Wo, WoutT);

    hipLaunchKernelGGL((gemm8<D_, D_, D_, NPAD_, NB_ / 256, 0>),
                       dim3((NB_ / 256) * (ROWS_ / 256)), dim3(512), 0, stream,
                       xn, WcatT, (const float*)nullptr, (void*)act);

    hipLaunchKernelGGL(chunk_scan1, dim3(3, CHUNKS_, B_), dim3(256), 0, stream, act, FA);
    hipLaunchKernelGGL(chunk_scan2, dim3(3, CHUNKS_, B_), dim3(256), 0, stream, act, FA, hs, outp);

    hipLaunchKernelGGL((gemm8<KPAD_, KPAD_, KPAD_, D_, D_ / 256, 1>),
                       dim3((D_ / 256) * (ROWS_ / 256)), dim3(512), 0, stream,
                       outp, WoutT, x, d_out);

    hipLaunchKernelGGL(copy_hidden, dim3((B_ * P_ + 255) / 256), dim3(256), 0, stream,
                       hs, out + (size_t)ROWS_ * D_);
}

// Round 13
// 423.984 us; speedup vs baseline: 1.0474x; 1.0474x over previous
//
#include <hip/hip_runtime.h>
#include <hip/hip_bf16.h>
#include <math.h>
#include <stdint.h>

typedef __bf16 bf16_t;
typedef bf16_t bf16x2 __attribute__((ext_vector_type(2)));
typedef bf16_t bf16x4 __attribute__((ext_vector_type(4)));
typedef bf16_t bf16x8 __attribute__((ext_vector_type(8)));
typedef float floatx4 __attribute__((ext_vector_type(4)));

#define B_     4
#define S_     4096
#define D_     1024
#define P_     1364
#define P3_    4092      // 3*P
#define NP_    5456      // 3P + P
#define NPAD_  5504      // act row stride
#define NB_    5632      // GEMM1 N padded to 22 tiles of 256
#define KPAD_  1408      // P_ padded (K of out-GEMM, 22 K-tiles)
#define ROWS_  16384     // B*S
#define CAP_   15.0f
#define EPS_   1e-6f
#define CHUNKS_ 32
#define CLEN_   128      // S_/CHUNKS_

// ---------------- fast transcendentals (bf16-accuracy) ----------------
__device__ __forceinline__ float fast_tanh(float x) {
    x = fminf(fmaxf(x, -15.f), 15.f);
    float e = __expf(2.f * x);
    return __fdividef(e - 1.f, e + 1.f);
}
// sigmoid(CAP*tanh(g/CAP)) == sigmoid(g) to <0.002 for all g.
__device__ __forceinline__ float fast_sig(float g) {
    return __fdividef(1.f, 1.f + __expf(-g));
}

__device__ __forceinline__ void vmcnt0() {
    asm volatile("s_waitcnt vmcnt(0)" ::: "memory");
}
__device__ __forceinline__ void vmcnt8() {
    asm volatile("s_waitcnt vmcnt(8)" ::: "memory");
}

// ---------------- RMSNorm: x fp32 [ROWS][D] -> xn bf16 [ROWS][D] ----------------
__global__ __launch_bounds__(256) void rmsnorm_kernel(const float* __restrict__ x,
                                                      const float* __restrict__ w,
                                                      bf16_t* __restrict__ xn) {
    int row = blockIdx.x;
    int tid = threadIdx.x;
    const float4 v = ((const float4*)(x + (size_t)row * D_))[tid];
    float ss = v.x * v.x + v.y * v.y + v.z * v.z + v.w * v.w;
    #pragma unroll
    for (int off = 32; off > 0; off >>= 1) ss += __shfl_down(ss, off);
    __shared__ float red[4];
    if ((tid & 63) == 0) red[tid >> 6] = ss;
    __syncthreads();
    float tot = red[0] + red[1] + red[2] + red[3];
    float scale = rsqrtf(tot * (1.0f / (float)D_) + EPS_);
    const float4 wv = ((const float4*)w)[tid];
    bf16x4 o;
    o[0] = (bf16_t)(v.x * scale * wv.x);
    o[1] = (bf16_t)(v.y * scale * wv.y);
    o[2] = (bf16_t)(v.z * scale * wv.z);
    o[3] = (bf16_t)(v.w * scale * wv.w);
    ((bf16x4*)(xn + (size_t)row * D_))[tid] = o;
}

// ---- pack W_gate [D][3P] + W_cell [D][P] fp32 -> Wcat^T bf16 [NB_][D] ----
__global__ __launch_bounds__(256) void pack_wcat(const float* __restrict__ Wg,
                                                 const float* __restrict__ Wc,
                                                 bf16_t* __restrict__ Wt) {
    __shared__ float tile[32][33];
    int kt = blockIdx.x * 32;
    int nt = blockIdx.y * 32;
    int tx = threadIdx.x & 31;
    int ty = threadIdx.x >> 5;
    #pragma unroll
    for (int i = 0; i < 4; i++) {
        int k = kt + ty + 8 * i;
        int n = nt + tx;
        float val = 0.f;
        if (n < P3_)      val = Wg[(size_t)k * P3_ + n];
        else if (n < NP_) val = Wc[(size_t)k * P_ + (n - P3_)];
        tile[ty + 8 * i][tx] = val;
    }
    __syncthreads();
    #pragma unroll
    for (int i = 0; i < 4; i++) {
        int n = nt + ty + 8 * i;
        int k = kt + tx;
        Wt[(size_t)n * D_ + k] = (bf16_t)tile[tx][ty + 8 * i];
    }
}

// ---- pack W_out [P][D] fp32 -> Wout^T bf16 [D][KPAD_] ----
__global__ __launch_bounds__(256) void pack_wout(const float* __restrict__ Wo,
                                                 bf16_t* __restrict__ Wt) {
    __shared__ float tile[32][33];
    int pt = blockIdx.x * 32;
    int dt = blockIdx.y * 32;
    int tx = threadIdx.x & 31;
    int ty = threadIdx.x >> 5;
    #pragma unroll
    for (int i = 0; i < 4; i++) {
        int p = pt + ty + 8 * i;
        int d = dt + tx;
        float val = (p < P_) ? Wo[(size_t)p * D_ + d] : 0.f;
        tile[ty + 8 * i][tx] = val;
    }
    __syncthreads();
    #pragma unroll
    for (int i = 0; i < 4; i++) {
        int d = dt + ty + 8 * i;
        int p = pt + tx;
        Wt[(size_t)d * KPAD_ + p] = (bf16_t)tile[tx][ty + 8 * i];
    }
}

// ---------------- 256x256 8-wave GEMM, 1 barrier/phase + spread staging (r12) ----------------
// Per phase: {ds_reads; stage?; setprio; MFMA; setprio; barrier}. No pre-MFMA
// barrier (waves desync; m114 overlap). Quadrant order Q1(m0-3,n0-1)
// Q2(m0-3,n2-3) Q3(m4-7,n2-3) Q4(m4-7,n0-1); stage t+2 INTO BUF c as regions
// free: B-lo@ph2, A-lo@ph3, A-hi+B-hi@ph4. End-of-tile counted vmcnt(8)
// retires exactly t+1's 8 units (FIFO, T4); never drains mid-loop. No
// sched_barrier (m141), no per-phase lgkm drains (r9). Zero-conflict swizzle.
// Operand-swap mfma(B,A): lane acc quad = 4 consecutive output cols.
template <int KTOT, int LDA, int LDB, int LDC, int NX, int EPI>
__global__ __launch_bounds__(512, 2) void gemm8(const bf16_t* __restrict__ A,
                                                const bf16_t* __restrict__ Bt,
                                                const float* __restrict__ res,
                                                void* __restrict__ outv) {
    constexpr int NT = KTOT / 64;
    static_assert(NT >= 4, "NT >= 4");
    __shared__ __align__(16) char smem[131072];

    const int tid  = threadIdx.x;
    const int wid  = tid >> 6;
    const int lane = tid & 63;
    const int l15  = lane & 15;
    const int sl4  = lane >> 4;
    const int sp    = sl4 ^ ((lane >> 1) & 3);          // read 16B-slot swizzle
    const int chunk = (lane & 3) ^ ((lane >> 3) & 3);   // stage-source inverse swizzle
    const int wrow = (wid >> 2) * 128;
    const int wcol = (wid & 3) * 64;

    // XCD map (verified: FETCH ~= compulsory): xcd owns 8 by-rows, bx-outer
    constexpr int MCH = (ROWS_ / 256) / 8;   // 8
    const int bid = blockIdx.x;
    const int xcd = bid & 7;
    const int idx = bid >> 3;
    const int bx  = idx / MCH;
    const int by  = xcd * MCH + (idx - bx * MCH);
    const int m0 = by * 256, n0 = bx * 256;

    const int srow = wid * 16 + (lane >> 2);
    const bf16_t* Asrc = A  + (size_t)(m0 + srow) * LDA + chunk * 8;
    const bf16_t* Bsrc = Bt + (size_t)(n0 + srow) * LDB + chunk * 8;
    const unsigned ldsA0 = (unsigned)(wid * 1024);
    const unsigned ldsB0 = 32768u + (unsigned)(wid * 1024);

    // half-unit stages: 2 global_load_lds each (one per kk)
    auto stageAlo = [&](int kt, int buf) {   // A rows 0-127
        #pragma unroll
        for (int kk = 0; kk < 2; kk++)
            __builtin_amdgcn_global_load_lds(
                (const unsigned*)(Asrc + kt * 64 + kk * 32),
                (unsigned*)(smem + ((unsigned)buf * 65536u + (unsigned)kk * 16384u + ldsA0)), 16, 0, 0);
    };
    auto stageAhi = [&](int kt, int buf) {   // A rows 128-255
        #pragma unroll
        for (int kk = 0; kk < 2; kk++)
            __builtin_amdgcn_global_load_lds(
                (const unsigned*)(Asrc + (size_t)128 * LDA + kt * 64 + kk * 32),
                (unsigned*)(smem + ((unsigned)buf * 65536u + (unsigned)kk * 16384u + 8192u + ldsA0)), 16, 0, 0);
    };
    auto stageBlo = [&](int kt, int buf) {   // B rows (out-cols) 0-127
        #pragma unroll
        for (int kk = 0; kk < 2; kk++)
            __builtin_amdgcn_global_load_lds(
                (const unsigned*)(Bsrc + kt * 64 + kk * 32),
                (unsigned*)(smem + ((unsigned)buf * 65536u + (unsigned)kk * 16384u + ldsB0)), 16, 0, 0);
    };
    auto stageBhi = [&](int kt, int buf) {   // B rows 128-255
        #pragma unroll
        for (int kk = 0; kk < 2; kk++)
            __builtin_amdgcn_global_load_lds(
                (const unsigned*)(Bsrc + (size_t)128 * LDB + kt * 64 + kk * 32),
                (unsigned*)(smem + ((unsigned)buf * 65536u + (unsigned)kk * 16384u + 8192u + ldsB0)), 16, 0, 0);
    };
    auto ldA = [&](int buf, int kk, int m) -> bf16x8 {
        return *(const bf16x8*)(smem + (buf * 65536 + kk * 16384 +
                                        (wrow + m * 16 + l15) * 64 + sp * 16));
    };
    auto ldB = [&](int buf, int kk, int n) -> bf16x8 {
        return *(const bf16x8*)(smem + (buf * 65536 + 32768 + kk * 16384 +
                                        (wcol + n * 16 + l15) * 64 + sp * 16));
    };

    floatx4 acc[8][4];
    #pragma unroll
    for (int m = 0; m < 8; m++)
        #pragma unroll
        for (int n = 0; n < 4; n++) acc[m][n] = (floatx4){0.f, 0.f, 0.f, 0.f};

    bf16x8 aq[8];   // A: [0..3]=kk0 m-set, [4..7]=kk1 m-set (lo then hi, rotated ph3)
    bf16x8 bq[4];   // B n0-1: live ph1 -> ph4
    bf16x8 bq2[4];  // B n2-3

    // prologue: tiles 0,1 fully staged (16 loads); counted wait retires tile0
    stageAlo(0, 0); stageAhi(0, 0); stageBlo(0, 0); stageBhi(0, 0);
    stageAlo(1, 1); stageAhi(1, 1); stageBlo(1, 1); stageBhi(1, 1);
    vmcnt8();
    __builtin_amdgcn_s_barrier();

    for (int t = 0; t < NT; ++t) {
        const int c = t & 1;
        const bool st = (t + 2 < NT);

        // ---- ph1: 12 reads (A-lo both kk, B-lo both kk); MFMA Q1
        #pragma unroll
        for (int m = 0; m < 4; m++) { aq[m] = ldA(c, 0, m); aq[m + 4] = ldA(c, 1, m); }
        #pragma unroll
        for (int n = 0; n < 2; n++) { bq[n] = ldB(c, 0, n); bq[n + 2] = ldB(c, 1, n); }
        __builtin_amdgcn_s_setprio(1);
        #pragma unroll
        for (int m = 0; m < 4; m++)
            #pragma unroll
            for (int n = 0; n < 2; n++) {
                acc[m][n] = __builtin_amdgcn_mfma_f32_16x16x32_bf16(bq[n], aq[m], acc[m][n], 0, 0, 0);
                acc[m][n] = __builtin_amdgcn_mfma_f32_16x16x32_bf16(bq[n + 2], aq[m + 4], acc[m][n], 0, 0, 0);
            }
        __builtin_amdgcn_s_setprio(0);
        __builtin_amdgcn_s_barrier();   // all waves' A-lo/B-lo reads retired

        // ---- ph2: 4 reads (B-hi); stage B-lo(t+2) into freed region; MFMA Q2
        #pragma unroll
        for (int n = 0; n < 2; n++) { bq2[n] = ldB(c, 0, n + 2); bq2[n + 2] = ldB(c, 1, n + 2); }
        if (st) stageBlo(t + 2, c);
        __builtin_amdgcn_s_setprio(1);
        #pragma unroll
        for (int m = 0; m < 4; m++)
            #pragma unroll
            for (int n = 0; n < 2; n++) {
                acc[m][n + 2] = __builtin_amdgcn_mfma_f32_16x16x32_bf16(bq2[n], aq[m], acc[m][n + 2], 0, 0, 0);
                acc[m][n + 2] = __builtin_amdgcn_mfma_f32_16x16x32_bf16(bq2[n + 2], aq[m + 4], acc[m][n + 2], 0, 0, 0);
            }
        __builtin_amdgcn_s_setprio(0);
        __builtin_amdgcn_s_barrier();

        // ---- ph3: 8 reads (A-hi overwrite aq); stage A-lo(t+2); MFMA Q3
        #pragma unroll
        for (int m = 0; m < 4; m++) { aq[m] = ldA(c, 0, m + 4); aq[m + 4] = ldA(c, 1, m + 4); }
        if (st) stageAlo(t + 2, c);
        __builtin_amdgcn_s_setprio(1);
        #pragma unroll
        for (int m = 0; m < 4; m++)
            #pragma unroll
            for (int n = 0; n < 2; n++) {
                acc[m + 4][n + 2] = __builtin_amdgcn_mfma_f32_16x16x32_bf16(bq2[n], aq[m], acc[m + 4][n + 2], 0, 0, 0);
                acc[m + 4][n + 2] = __builtin_amdgcn_mfma_f32_16x16x32_bf16(bq2[n + 2], aq[m + 4], acc[m + 4][n + 2], 0, 0, 0);
            }
        __builtin_amdgcn_s_setprio(0);
        __builtin_amdgcn_s_barrier();   // all waves' A-hi/B-hi reads retired

        // ---- ph4: stage A-hi+B-hi(t+2); reg-only Q4; counted vmcnt; publish
        if (st) { stageAhi(t + 2, c); stageBhi(t + 2, c); }
        __builtin_amdgcn_s_setprio(1);
        #pragma unroll
        for (int m = 0; m < 4; m++)
            #pragma unroll
            for (int n = 0; n < 2; n++) {
                acc[m + 4][n] = __builtin_amdgcn_mfma_f32_16x16x32_bf16(bq[n], aq[m], acc[m + 4][n], 0, 0, 0);
                acc[m + 4][n] = __builtin_amdgcn_mfma_f32_16x16x32_bf16(bq[n + 2], aq[m + 4], acc[m + 4][n], 0, 0, 0);
            }
        __builtin_amdgcn_s_setprio(0);
        if (st)                vmcnt8();   // retire t+1's 8 units; t+2's stay in flight
        else if (t + 2 == NT)  vmcnt0();   // tail: only t+1's units outstanding
        __builtin_amdgcn_s_barrier();      // publish buf c^1
    }

    // transposed C/D (operand swap): lane holds rows m0+wrow+m*16+l15,
    // 4 consecutive cols n0+wcol+n*16+sl4*4 .. +3
    if constexpr (EPI == 0) {
        bf16_t* O = (bf16_t*)outv;
        #pragma unroll
        for (int m = 0; m < 8; m++) {
            const int row = m0 + wrow + m * 16 + l15;
            #pragma unroll
            for (int n = 0; n < 4; n++) {
                const int cb = n0 + wcol + n * 16 + sl4 * 4;
                if (cb < NP_) {           // packs never straddle NP_/P3_ (all %4==0)
                    const bool sg = cb < P3_;
                    bf16x4 o;
                    #pragma unroll
                    for (int r = 0; r < 4; r++) {
                        float g = acc[m][n][r];
                        o[r] = (bf16_t)(sg ? fast_sig(g) : fast_tanh(g));
                    }
                    *(bf16x4*)(O + (size_t)row * LDC + cb) = o;
                }
            }
        }
    } else {
        float* O = (float*)outv;
        #pragma unroll
        for (int m = 0; m < 8; m++) {
            const int row = m0 + wrow + m * 16 + l15;
            #pragma unroll
            for (int n = 0; n < 4; n++) {
                const int cb = n0 + wcol + n * 16 + sl4 * 4;
                const float4 rv = *(const float4*)(res + (size_t)row * LDC + cb);
                float4 ov;
                ov.x = rv.x + acc[m][n][0];
                ov.y = rv.y + acc[m][n][1];
                ov.z = rv.z + acc[m][n][2];
                ov.w = rv.w + acc[m][n][3];
                *(float4*)(O + (size_t)row * LDC + cb) = ov;
            }
        }
    }
}

// ---------------- chunked linear recurrence (r6 scalar form + MLP unroll) ----------------
// Latency-bound: 768 blocks (12 waves/CU) is the TLP sweet spot — x2
// vectorization (384 blocks) regressed twice (r8, r12). Unroll batches the
// t-independent loads (MLP) without touching occupancy.
// act layout per row (bf16, stride NPAD_): [0,P): i | [P,2P): f | [2P,3P): o | [3P,4P): tanh(c)
__global__ __launch_bounds__(256) void chunk_scan1(const bf16_t* __restrict__ act,
                                                   float* __restrict__ FA) {
    int p = blockIdx.x * 256 + threadIdx.x;
    int c = blockIdx.y;
    int b = blockIdx.z;
    if (p >= P_) return;
    const bf16_t* base = act + (size_t)(b * S_ + c * CLEN_) * NPAD_;
    float F = 1.f, Acc = 0.f;
    #pragma unroll 4
    for (int t = 0; t < CLEN_; t++) {
        const bf16_t* r = base + (size_t)t * NPAD_;
        float iv = (float)r[p];
        float fv = (float)r[P_ + p];
        float tc = (float)r[P3_ + p];
        Acc = fv * Acc + iv * tc;
        F *= fv;
    }
    size_t idx = (((size_t)b * CHUNKS_ + c) * P_ + p) * 2;
    FA[idx]     = F;
    FA[idx + 1] = Acc;
}

__global__ __launch_bounds__(256) void chunk_scan2(const bf16_t* __restrict__ act,
                                                   const float* __restrict__ FA,
                                                   const float* __restrict__ h0,
                                                   bf16_t* __restrict__ outp) {
    int p = blockIdx.x * 256 + threadIdx.x;
    int c = blockIdx.y;
    int b = blockIdx.z;
    if (p >= KPAD_) return;
    if (p >= P_) {  // zero-fill K-pad columns for GEMM2
        bf16_t z = (bf16_t)0.f;
        for (int t = 0; t < CLEN_; t++)
            outp[(size_t)(b * S_ + c * CLEN_ + t) * KPAD_ + p] = z;
        return;
    }
    float h = h0[(size_t)b * P_ + p];
    for (int j = 0; j < c; j++) {
        size_t idx = (((size_t)b * CHUNKS_ + j) * P_ + p) * 2;
        h = FA[idx + 1] + FA[idx] * h;
    }
    const bf16_t* base = act + (size_t)(b * S_ + c * CLEN_) * NPAD_;
    bf16_t* ob = outp + (size_t)(b * S_ + c * CLEN_) * KPAD_;
    #pragma unroll 2
    for (int t = 0; t < CLEN_; t++) {
        const bf16_t* r = base + (size_t)t * NPAD_;
        float iv = (float)r[p];
        float fv = (float)r[P_ + p];
        float ov = (float)r[2 * P_ + p];
        float tc = (float)r[P3_ + p];
        h = fv * h + iv * tc;
        ob[(size_t)t * KPAD_ + p] = (bf16_t)(ov * fast_tanh(h));
    }
}

__global__ void copy_hidden(const float* __restrict__ hs, float* __restrict__ dst) {
    int i = blockIdx.x * 256 + threadIdx.x;
    if (i < B_ * P_) dst[i] = hs[i];
}

extern "C" void kernel_launch(void* const* d_in, const int* in_sizes, int n_in,
                              void* d_out, int out_size, void* d_ws, size_t ws_size,
                              hipStream_t stream) {
    const float* x   = (const float*)d_in[0];
    const float* hs  = (const float*)d_in[1];
    const float* lnw = (const float*)d_in[2];
    const float* Wg  = (const float*)d_in[3];
    const float* Wc  = (const float*)d_in[4];
    const float* Wo  = (const float*)d_in[5];
    float* out = (float*)d_out;

    char* ws = (char*)d_ws;
    size_t off = 0;
    auto alloc = [&](size_t bytes) {
        void* p = ws + off;
        off += (bytes + 255) & ~(size_t)255;
        return p;
    };
    bf16_t* xn_outp = (bf16_t*)alloc((size_t)ROWS_ * KPAD_ * 2);   // xn then outputs
    bf16_t* act     = (bf16_t*)alloc((size_t)ROWS_ * NPAD_ * 2);
    bf16_t* WcatT   = (bf16_t*)alloc((size_t)NB_ * D_ * 2);
    bf16_t* WoutT   = (bf16_t*)alloc((size_t)D_ * KPAD_ * 2);
    float*  FA      = (float*)alloc((size_t)B_ * CHUNKS_ * P_ * 2 * 4);

    bf16_t* xn   = xn_outp;
    bf16_t* outp = xn_outp;

    hipLaunchKernelGGL(rmsnorm_kernel, dim3(ROWS_), dim3(256), 0, stream, x, lnw, xn);
    hipLaunchKernelGGL(pack_wcat, dim3(32, NB_ / 32), dim3(256), 0, stream, Wg, Wc, WcatT);
    hipLaunchKernelGGL(pack_wout, dim3(KPAD_ / 32, D_ / 32), dim3(256), 0, stream, Wo, WoutT);

    hipLaunchKernelGGL((gemm8<D_, D_, D_, NPAD_, NB_ / 256, 0>),
                       dim3((NB_ / 256) * (ROWS_ / 256)), dim3(512), 0, stream,
                       xn, WcatT, (const float*)nullptr, (void*)act);

    hipLaunchKernelGGL(chunk_scan1, dim3(6, CHUNKS_, B_), dim3(256), 0, stream, act, FA);
    hipLaunchKernelGGL(chunk_scan2, dim3(6, CHUNKS_, B_), dim3(256), 0, stream, act, FA, hs, outp);

    hipLaunchKernelGGL((gemm8<KPAD_, KPAD_, KPAD_, D_, D_ / 256, 1>),
                       dim3((D_ / 256) * (ROWS_ / 256)), dim3(512), 0, stream,
                       outp, WoutT, x, d_out);

    hipLaunchKernelGGL(copy_hidden, dim3((B_ * P_ + 255) / 256), dim3(256), 0, stream,
                       hs, out + (size_t)ROWS_ * D_);
}